// Round 7
// baseline (318.847 us; speedup 1.0000x reference)
//
#include <hip/hip_runtime.h>
#include <hip/hip_bf16.h>
#include <math.h>

// ---------------------------------------------------------------------------
// ModelPassMessage: 7-layer graph conv.
// R1: CSR build + gather aggregation (replaced atomic scatter). 1631->1032us.
// R2: gather MLP-widened. 1032->736us.  R3: conv64 LDS-free. 736->640us.
// R4: bf16 hidden states. 640->493us.  R5: bf16 aggr + wide gather. ->442us.
// R6: fixed-width slot table, one prep kernel. ->419us.
// R7 FAILED (419->510): per-layer gather+conv fusion; reverted.
// R8: 4-byte packed slots. ->415us.
// R9: LDS-bucketed prep, 2B slots, exact f32 he. ->391us.
// R10 NULL (->387.6): 2x gather MLP + speculative loads.
// R11 FAILED (->1241): cooperative all-layer fusion; grid.sync() flushes
//     per-XCD L2 -> 391MB refetch/launch. Reverted.
// R12: fused final gather+conv; conv64 16B loads. ->383.
// R13: lane-serial gather (4 nodes x 16 lanes, zero-row padding). ->372.
// R14: MFMA conv (mfma_f32_16x16x32_bf16, Wb frags in prep, he/bias in
//     acc init, LDS-tiled epilogue). ->293.5. Gathers now ~2/3 of runtime.
// R15: src-range two-pass gather (cache blocking). h (6.4MB) > 4MiB/XCD L2
//     -> random row reads thrash to L3 (~3.6 TB/s effective). Split each
//     slot row in build: src<N/2 fills front, src>=N/2 fills back (deg
//     packed lo|hi<<16; >=3-slot pad gap for deg<=61, dataset max ~45).
//     Gather = 2 dispatches/layer: pass A reads ONLY rows [0,N/2) (3.2MB,
//     fits every XCD L2), writes bf16 partial; pass B reads [N/2,N), adds
//     partial, writes final. Kernel boundary separates phases so the whole
//     chip's read set is one half at a time. final_fused: both regions
//     in-kernel.
// ---------------------------------------------------------------------------

typedef __hip_bfloat16 bf16;

#define SLOTW 64   // max degree supported; Poisson(16) max over 50k ~45
#define EPB   4096 // edges per phase-1 tile block
#define NPB   256  // nodes per bucket (dst>>8)
#define CAP   5120 // per-bucket edge capacity (mean 4096, sigma ~64)
#define WBB   24   // W-fragment build blocks: 6*4*4*64 threads / 256

typedef __attribute__((ext_vector_type(8))) short short8v;
typedef __attribute__((ext_vector_type(4))) float f32x4;

__device__ inline float b2f(unsigned u) {
    return __uint_as_float(u << 16);
}
__device__ inline unsigned short f2b(float f) {
    union { float f; unsigned u; } v;
    v.f = f;
    unsigned r = v.u + 0x7FFF + ((v.u >> 16) & 1);  // RNE
    return (unsigned short)(r >> 16);
}

// ---------------- phase 1: edge bucketing (+W frags, nf->bf16) ------------
__global__ __launch_bounds__(256) void bucket_kernel(
    const int* __restrict__ src, const int* __restrict__ dst,
    const float* __restrict__ ef, uint2* __restrict__ barr,
    int* __restrict__ bfill, int n_edges, int n_tiles, int n_buckets,
    const float* __restrict__ W1, const float* __restrict__ Wmid,
    bf16* __restrict__ Wb, const float* __restrict__ node_feat,
    bf16* __restrict__ nfb, int n_quads) {
    __shared__ int cnt[256];
    __shared__ int pfx[256];   // inclusive scan of cnt
    __shared__ int gbase[256];
    __shared__ uint2 stage[EPB];
    __shared__ int didx[EPB];

    if (blockIdx.x >= n_tiles) {
        int bx = blockIdx.x - n_tiles;
        if (bx < WBB) {
            // MFMA B-fragment build: Wb[l][kt][nt][lane][j] = W_l[n][k],
            // n = nt*16 + (lane&15), k = kt*32 + (lane>>4)*8 + j.
            int fidx = bx * 256 + threadIdx.x;  // < 6144
            int lane = fidx & 63;
            int nt = (fidx >> 6) & 3;
            int kt = (fidx >> 8) & 3;
            int l = fidx >> 10;
            if (l < 6) {
                int n = nt * 16 + (lane & 15);
                int k0 = kt * 32 + (lane >> 4) * 8;
                const float* Wsrc =
                    (l == 0) ? W1 : Wmid + (size_t)(l - 1) * 64 * 129;
                const float* wp = Wsrc + n * 129 + k0;
                unsigned short us[8];
#pragma unroll
                for (int j = 0; j < 8; ++j) us[j] = f2b(wp[j]);
                uint4 pk;
                pk.x = (unsigned)us[0] | ((unsigned)us[1] << 16);
                pk.y = (unsigned)us[2] | ((unsigned)us[3] << 16);
                pk.z = (unsigned)us[4] | ((unsigned)us[5] << 16);
                pk.w = (unsigned)us[6] | ((unsigned)us[7] << 16);
                ((uint4*)Wb)[fidx] = pk;
            }
        } else {
            int q = (bx - WBB) * 256 + threadIdx.x;
            if (q >= n_quads) return;
            float4 v = ((const float4*)node_feat)[q];
            ushort4 u;
            u.x = f2b(v.x); u.y = f2b(v.y); u.z = f2b(v.z); u.w = f2b(v.w);
            ((ushort4*)nfb)[q] = u;
        }
        return;
    }

    const int t = threadIdx.x;
    cnt[t] = 0;
    __syncthreads();

    const int e0 = blockIdx.x * EPB;
    int b[16];
    int r[16];
    uint2 d[16];
#pragma unroll
    for (int i = 0; i < 16; ++i) {
        int e = e0 + i * 256 + t;
        if (e < n_edges) {
            int dv = dst[e];
            int bb = dv >> 8;
            b[i] = bb;
            uint2 rec;
            rec.x = (unsigned)(src[e] & 0xffff) | ((unsigned)(dv & (NPB - 1)) << 16);
            rec.y = __float_as_uint(ef[e]);
            d[i] = rec;
            r[i] = atomicAdd(&cnt[bb], 1);
        } else {
            b[i] = -1;
        }
    }
    __syncthreads();

    // inclusive Hillis-Steele scan of cnt -> pfx
    pfx[t] = cnt[t];
    __syncthreads();
    for (int off = 1; off < 256; off <<= 1) {
        int add = (t >= off) ? pfx[t - off] : 0;
        __syncthreads();
        pfx[t] += add;
        __syncthreads();
    }

    if (t < n_buckets && cnt[t] > 0) gbase[t] = atomicAdd(&bfill[t], cnt[t]);
    __syncthreads();

    // scatter into LDS stage (dense positions), record global dest index
#pragma unroll
    for (int i = 0; i < 16; ++i) {
        if (b[i] >= 0) {
            int bb = b[i];
            int pos = pfx[bb] - cnt[bb] + r[i];
            stage[pos] = d[i];
            int gi = gbase[bb] + r[i];
            didx[pos] = (gi < CAP) ? bb * CAP + gi : -1;
        }
    }
    __syncthreads();

    // coalesced flush: consecutive positions -> consecutive global addrs
    const int total = pfx[255];
    for (int k = t; k < total; k += 256) {
        int di = didx[k];
        if (di >= 0) barr[di] = stage[k];
    }
}

// ---------------- phase 2: build split slot rows + deg + he in LDS --------
// One block per bucket. Slot row split by src half: src<half fills from the
// front, src>=half from the back. deg packed lo | (hi<<16) (each capped 61,
// guaranteeing a >=3-entry pad gap so pass quad boundaries never cross).
// Padding = index n_nodes (the all-zero row). Block 0 zeroes row N of
// nfb/hA/hB every launch (workspace re-poisoned between calls).
__global__ __launch_bounds__(512) void build_kernel(
    const uint2* __restrict__ barr, const int* __restrict__ bfill,
    unsigned short* __restrict__ slots, int* __restrict__ deg,
    float* __restrict__ he, bf16* __restrict__ nfb, bf16* __restrict__ hA,
    bf16* __restrict__ hB, int n_nodes, int half) {
    __shared__ unsigned short rows[NPB * SLOTW];  // 32KB
    __shared__ int llo[NPB];
    __shared__ int lhi[NPB];
    __shared__ float lhe[NPB];
    const int bkt = blockIdx.x;
    const int t = threadIdx.x;
    for (int i = t; i < NPB; i += 512) {
        llo[i] = 0;
        lhi[i] = 0;
        lhe[i] = 0.f;
    }
    const unsigned padv = (unsigned)n_nodes & 0xffff;
    const unsigned pat = padv | (padv << 16);
    uint4* rz = (uint4*)rows;
    for (int i = t; i < NPB * SLOTW / 8; i += 512)
        rz[i] = make_uint4(pat, pat, pat, pat);
    if (bkt == 0 && t < 24) {
        int which = t >> 3, q = t & 7;
        unsigned short* base = which == 0 ? (unsigned short*)nfb
                             : which == 1 ? (unsigned short*)hA
                                          : (unsigned short*)hB;
        ((uint4*)(base + (size_t)n_nodes * 64))[q] = make_uint4(0, 0, 0, 0);
    }
    __syncthreads();
    int cnt = bfill[bkt];
    if (cnt > CAP) cnt = CAP;
    const uint2* eb = barr + (size_t)bkt * CAP;
    for (int k = t; k < cnt; k += 512) {
        uint2 rec = eb[k];
        int local = (rec.x >> 16) & (NPB - 1);
        int s = (int)(rec.x & 0xffff);
        atomicAdd(&lhe[local], __uint_as_float(rec.y));
        if (s < half) {
            int p = atomicAdd(&llo[local], 1);
            if (p < 61) rows[local * SLOTW + p] = (unsigned short)s;
        } else {
            int p = atomicAdd(&lhi[local], 1);
            if (p < 61) rows[local * SLOTW + 63 - p] = (unsigned short)s;
        }
    }
    __syncthreads();
    const int n0 = bkt * NPB;
    int nn = n_nodes - n0;
    if (nn > NPB) nn = NPB;
    if (nn <= 0) return;
    for (int i = t; i < nn; i += 512) {
        int lo = llo[i] < 61 ? llo[i] : 61;
        int hi = lhi[i] < 61 ? lhi[i] : 61;
        deg[n0 + i] = lo | (hi << 16);
        he[n0 + i] = lhe[i];
    }
    const uint4* rsrc = (const uint4*)rows;
    uint4* rdst = (uint4*)(slots + (size_t)n0 * SLOTW);
    for (int i = t; i < nn * 8; i += 512) rdst[i] = rsrc[i];
}

// ---------------- per-layer kernels ---------------------------------------

// R15 two-pass gather: wave = 4 nodes x 16 feature-lanes; lane serially
// accumulates 4 features, 4 edges/iter. pass 0: quads [0, ceil(lo/4)) (src
// half A only), store bf16 partial. pass 1: quads [16-ceil(hi/4), 16) (half
// B), add partial, store final. Pads hit the all-zero row at index N.
__global__ __launch_bounds__(256) void gather_aggr_kernel(
    const bf16* __restrict__ h, const int* __restrict__ deg,
    const unsigned short* __restrict__ slots, bf16* __restrict__ aggr,
    int n_nodes, int pass) {
    const int lane = threadIdx.x & 63;
    const int wave = threadIdx.x >> 6;
    int node = blockIdx.x * 16 + wave * 4 + (lane >> 4);
    const int nc = node < n_nodes ? node : n_nodes - 1;
    const int fo = (lane & 15) * 4;  // 4 bf16 = 8B per lane

    unsigned dpk = (unsigned)deg[nc];
    int t0, t1;
    if (pass == 0) {
        int lo = (int)(dpk & 0xffffu);
        int it = (lo + 3) >> 2;
        int o = __shfl_xor(it, 16, 64);
        it = it > o ? it : o;
        o = __shfl_xor(it, 32, 64);
        it = it > o ? it : o;
        t0 = 0;
        t1 = it;
    } else {
        int hi = (int)(dpk >> 16);
        int qs = 16 - ((hi + 3) >> 2);
        int o = __shfl_xor(qs, 16, 64);
        qs = qs < o ? qs : o;
        o = __shfl_xor(qs, 32, 64);
        qs = qs < o ? qs : o;
        t0 = qs;
        t1 = 16;
    }

    const uint2* srow = (const uint2*)(slots + (size_t)nc * SLOTW);
    const unsigned short* hs = (const unsigned short*)h;

    float a0 = 0.f, a1 = 0.f, a2 = 0.f, a3 = 0.f;
    for (int t = t0; t < t1; ++t) {
        uint2 s = srow[t];  // broadcast across the 16-lane group
        unsigned p0 = s.x & 0xffff, p1 = s.x >> 16;
        unsigned p2 = s.y & 0xffff, p3 = s.y >> 16;
        uint2 u0 = *(const uint2*)(hs + (size_t)p0 * 64 + fo);
        uint2 u1 = *(const uint2*)(hs + (size_t)p1 * 64 + fo);
        uint2 u2 = *(const uint2*)(hs + (size_t)p2 * 64 + fo);
        uint2 u3 = *(const uint2*)(hs + (size_t)p3 * 64 + fo);
        a0 += (b2f(u0.x & 0xffff) + b2f(u1.x & 0xffff)) +
              (b2f(u2.x & 0xffff) + b2f(u3.x & 0xffff));
        a1 += (b2f(u0.x >> 16) + b2f(u1.x >> 16)) +
              (b2f(u2.x >> 16) + b2f(u3.x >> 16));
        a2 += (b2f(u0.y & 0xffff) + b2f(u1.y & 0xffff)) +
              (b2f(u2.y & 0xffff) + b2f(u3.y & 0xffff));
        a3 += (b2f(u0.y >> 16) + b2f(u1.y >> 16)) +
              (b2f(u2.y >> 16) + b2f(u3.y >> 16));
    }

    if (node < n_nodes) {
        unsigned short* ap = (unsigned short*)aggr + (size_t)node * 64 + fo;
        if (pass == 1) {
            uint2 pv = *(const uint2*)ap;
            a0 += b2f(pv.x & 0xffff);
            a1 += b2f(pv.x >> 16);
            a2 += b2f(pv.y & 0xffff);
            a3 += b2f(pv.y >> 16);
        }
        uint2 pk;
        pk.x = (unsigned)f2b(a0) | ((unsigned)f2b(a1) << 16);
        pk.y = (unsigned)f2b(a2) | ((unsigned)f2b(a3) << 16);
        *(uint2*)ap = pk;
    }
}

// R14 MFMA conv: block = 64 nodes, 4 waves; wave computes 16-row stripe of
// C = [h|aggr][64x128] @ W[128x64] via 4kt x 4nt mfma_f32_16x16x32_bf16.
__global__ __launch_bounds__(256) void conv_mfma_kernel(
    const bf16* __restrict__ h, const bf16* __restrict__ aggr,
    const float* __restrict__ he, const bf16* __restrict__ Wb,
    const float* __restrict__ Wraw, const float* __restrict__ b,
    bf16* __restrict__ out, int n_nodes, int act) {
    __shared__ __align__(16) unsigned short tile[4][16][72];
    const int lane = threadIdx.x & 63;
    const int w = threadIdx.x >> 6;
    const int nblk = blockIdx.x * 64 + w * 16;  // stripe base node

    int arow_n = nblk + (lane & 15);
    int arn = arow_n < n_nodes ? arow_n : n_nodes - 1;
    const int chunk = lane >> 4;
    const uint4* hrow = (const uint4*)(h + (size_t)arn * 64);
    const uint4* grow = (const uint4*)(aggr + (size_t)arn * 64);

    union AU { uint4 u; short8v s; };
    AU a[4];
    a[0].u = hrow[chunk];
    a[1].u = hrow[4 + chunk];
    a[2].u = grow[chunk];
    a[3].u = grow[4 + chunk];

    f32x4 acc[4];
    float hev[4];
    const int mb = nblk + (lane >> 4) * 4;
#pragma unroll
    for (int i = 0; i < 4; ++i) {
        int rr = mb + i;
        hev[i] = he[rr < n_nodes ? rr : n_nodes - 1];
    }
#pragma unroll
    for (int nt = 0; nt < 4; ++nt) {
        int n = nt * 16 + (lane & 15);
        float bb = b[n];
        float wh = Wraw[n * 129 + 128];
#pragma unroll
        for (int i = 0; i < 4; ++i) acc[nt][i] = bb + hev[i] * wh;
    }

    const uint4* wb4 = (const uint4*)Wb;
#pragma unroll
    for (int kt = 0; kt < 4; ++kt) {
#pragma unroll
        for (int nt = 0; nt < 4; ++nt) {
            AU bf;
            bf.u = wb4[(kt * 4 + nt) * 64 + lane];
            acc[nt] = __builtin_amdgcn_mfma_f32_16x16x32_bf16(
                a[kt].s, bf.s, acc[nt], 0, 0, 0);
        }
    }

#pragma unroll
    for (int nt = 0; nt < 4; ++nt) {
#pragma unroll
        for (int i = 0; i < 4; ++i) {
            float v = acc[nt][i];
            v = (act == 1) ? fmaxf(v, 0.f) : 1.f / (1.f + expf(-v));
            tile[w][(lane >> 4) * 4 + i][nt * 16 + (lane & 15)] = f2b(v);
        }
    }
    __syncthreads();
    const int rr = lane >> 2, cc = lane & 3;
    int nodeo = nblk + rr;
    if (nodeo < n_nodes) {
        uint4* orow = (uint4*)((unsigned short*)out + (size_t)nodeo * 64);
        orow[cc] = *(const uint4*)&tile[w][rr][cc * 8];
        orow[cc + 4] = *(const uint4*)&tile[w][rr][(cc + 4) * 8];
    }
}

// R15 fused final layer: both gather regions in-kernel (register acc), then
// per-lane 4-feature dot + 16-lane shuffle reduce.
__global__ __launch_bounds__(256) void final_fused_kernel(
    const bf16* __restrict__ h, const int* __restrict__ deg,
    const unsigned short* __restrict__ slots, const float* __restrict__ he,
    const float* __restrict__ W2, const float* __restrict__ b2,
    float* __restrict__ out, int n_nodes) {
    const int lane = threadIdx.x & 63;
    const int wave = threadIdx.x >> 6;
    int node = blockIdx.x * 16 + wave * 4 + (lane >> 4);
    const int nc = node < n_nodes ? node : n_nodes - 1;
    const int fl = lane & 15;
    const int fo = fl * 4;

    unsigned dpk = (unsigned)deg[nc];
    int lo = (int)(dpk & 0xffffu);
    int hi = (int)(dpk >> 16);
    int itA = (lo + 3) >> 2;
    {
        int o = __shfl_xor(itA, 16, 64);
        itA = itA > o ? itA : o;
        o = __shfl_xor(itA, 32, 64);
        itA = itA > o ? itA : o;
    }
    int qs = 16 - ((hi + 3) >> 2);
    {
        int o = __shfl_xor(qs, 16, 64);
        qs = qs < o ? qs : o;
        o = __shfl_xor(qs, 32, 64);
        qs = qs < o ? qs : o;
    }

    const uint2* srow = (const uint2*)(slots + (size_t)nc * SLOTW);
    const unsigned short* hs = (const unsigned short*)h;

    float a0 = 0.f, a1 = 0.f, a2 = 0.f, a3 = 0.f;
#pragma unroll 1
    for (int seg = 0; seg < 2; ++seg) {
        int t = seg == 0 ? 0 : qs;
        int te = seg == 0 ? itA : 16;
        for (; t < te; ++t) {
            uint2 s = srow[t];
            unsigned p0 = s.x & 0xffff, p1 = s.x >> 16;
            unsigned p2 = s.y & 0xffff, p3 = s.y >> 16;
            uint2 u0 = *(const uint2*)(hs + (size_t)p0 * 64 + fo);
            uint2 u1 = *(const uint2*)(hs + (size_t)p1 * 64 + fo);
            uint2 u2 = *(const uint2*)(hs + (size_t)p2 * 64 + fo);
            uint2 u3 = *(const uint2*)(hs + (size_t)p3 * 64 + fo);
            a0 += (b2f(u0.x & 0xffff) + b2f(u1.x & 0xffff)) +
                  (b2f(u2.x & 0xffff) + b2f(u3.x & 0xffff));
            a1 += (b2f(u0.x >> 16) + b2f(u1.x >> 16)) +
                  (b2f(u2.x >> 16) + b2f(u3.x >> 16));
            a2 += (b2f(u0.y & 0xffff) + b2f(u1.y & 0xffff)) +
                  (b2f(u2.y & 0xffff) + b2f(u3.y & 0xffff));
            a3 += (b2f(u0.y >> 16) + b2f(u1.y >> 16)) +
                  (b2f(u2.y >> 16) + b2f(u3.y >> 16));
        }
    }

    uint2 hu = *(const uint2*)(hs + (size_t)nc * 64 + fo);
    float h0 = b2f(hu.x & 0xffff), h1 = b2f(hu.x >> 16);
    float h2 = b2f(hu.y & 0xffff), h3 = b2f(hu.y >> 16);
    const int f = fo;
    float s0 = W2[f] * h0 + W2[f + 1] * h1 + W2[f + 2] * h2 + W2[f + 3] * h3 +
               W2[64 + f] * a0 + W2[65 + f] * a1 + W2[66 + f] * a2 +
               W2[67 + f] * a3;
    float s1 = W2[129 + f] * h0 + W2[130 + f] * h1 + W2[131 + f] * h2 +
               W2[132 + f] * h3 + W2[193 + f] * a0 + W2[194 + f] * a1 +
               W2[195 + f] * a2 + W2[196 + f] * a3;
#pragma unroll
    for (int off = 1; off < 16; off <<= 1) {
        s0 += __shfl_xor(s0, off, 64);
        s1 += __shfl_xor(s1, off, 64);
    }
    if (fl == 0 && node < n_nodes) {
        float hev = he[node];
        out[(size_t)node * 2] = s0 + W2[128] * hev + b2[0];
        out[(size_t)node * 2 + 1] = s1 + W2[257] * hev + b2[1];
    }
}

extern "C" void kernel_launch(void* const* d_in, const int* in_sizes, int n_in,
                              void* d_out, int out_size, void* d_ws,
                              size_t ws_size, hipStream_t stream) {
    const float* node_feat = (const float*)d_in[0];
    const float* edge_feat = (const float*)d_in[1];
    const int* src = (const int*)d_in[2];
    const int* dst = (const int*)d_in[3];
    const float* W1 = (const float*)d_in[4];
    const float* b1 = (const float*)d_in[5];
    const float* Wmid = (const float*)d_in[6];
    const float* bmid = (const float*)d_in[7];
    const float* W2 = (const float*)d_in[8];
    const float* b2 = (const float*)d_in[9];
    float* out = (float*)d_out;

    const int N = in_sizes[0] / 64;  // 50000
    const int E = in_sizes[1];       // 800000
    const int NBKT = (N + NPB - 1) / NPB;  // 196
    const int HALF = N / 2;
    const size_t R = (size_t)(N + 1) * 64;  // rows incl. zero row

    // workspace layout (sections 16B-aligned)
    float* he = (float*)d_ws;                              // N f32
    bf16* Wb = (bf16*)(he + N);                            // 6*8192 bf16
    bf16* aggr = Wb + 6 * 8192;                            // N*64 bf16
    bf16* hA = aggr + (size_t)N * 64;                      // (N+1)*64 bf16
    bf16* hB = hA + R;                                     // (N+1)*64 bf16
    bf16* nfb = hB + R;                                    // (N+1)*64 bf16
    unsigned short* slots = (unsigned short*)(nfb + R);    // N*SLOTW
    int* deg = (int*)(slots + (size_t)N * SLOTW);          // N
    int* bfill = deg + N;                                  // NBKT
    uint2* barr = (uint2*)(((uintptr_t)(bfill + NBKT) + 15) & ~(uintptr_t)15);
    // barr: NBKT*CAP uint2 = ~8 MB; total ~41 MB

    // --- prep ---
    hipMemsetAsync(bfill, 0, (size_t)NBKT * sizeof(int), stream);
    const int n_tiles = (E + EPB - 1) / EPB;
    const int n_quads = N * 16;
    const int CB = (n_quads + 255) / 256;
    bucket_kernel<<<n_tiles + WBB + CB, 256, 0, stream>>>(
        src, dst, edge_feat, barr, bfill, E, n_tiles, NBKT, W1, Wmid, Wb,
        node_feat, nfb, n_quads);
    build_kernel<<<NBKT, 512, 0, stream>>>(barr, bfill, slots, deg, he, nfb,
                                           hA, hB, N, HALF);

    // --- 7 layers ---
    const int conv_blocks = (N + 63) / 64;
    const int gather_blocks = (N + 15) / 16;

    // layer 0 (bf16 node features)
    gather_aggr_kernel<<<gather_blocks, 256, 0, stream>>>(nfb, deg, slots,
                                                          aggr, N, 0);
    gather_aggr_kernel<<<gather_blocks, 256, 0, stream>>>(nfb, deg, slots,
                                                          aggr, N, 1);
    conv_mfma_kernel<<<conv_blocks, 256, 0, stream>>>(nfb, aggr, he, Wb, W1,
                                                      b1, hA, N, 1);

    // layers 1..5
    bf16* bufs[2] = {hA, hB};
    const bf16* hin = hA;
    for (int l = 1; l < 6; ++l) {
        gather_aggr_kernel<<<gather_blocks, 256, 0, stream>>>(hin, deg, slots,
                                                              aggr, N, 0);
        gather_aggr_kernel<<<gather_blocks, 256, 0, stream>>>(hin, deg, slots,
                                                              aggr, N, 1);
        int act = (l - 1) < 4 ? 1 : 2;  // mid layers 0..3 relu, 4 sigmoid
        bf16* hout = bufs[l & 1];
        conv_mfma_kernel<<<conv_blocks, 256, 0, stream>>>(
            hin, aggr, he, Wb + (size_t)l * 8192,
            Wmid + (size_t)(l - 1) * 64 * 129, bmid + (size_t)(l - 1) * 64,
            hout, N, act);
        hin = hout;
    }

    // final layer: fused gather + 2-output conv
    final_fused_kernel<<<gather_blocks, 256, 0, stream>>>(hin, deg, slots, he,
                                                          W2, b2, out, N);
}

// Round 8
// 293.289 us; speedup vs baseline: 1.0871x; 1.0871x over previous
//
#include <hip/hip_runtime.h>
#include <hip/hip_bf16.h>
#include <math.h>

// ---------------------------------------------------------------------------
// ModelPassMessage: 7-layer graph conv.
// R1: CSR build + gather aggregation (replaced atomic scatter). 1631->1032us.
// R2: gather MLP-widened. 1032->736us.  R3: conv64 LDS-free. 736->640us.
// R4: bf16 hidden states. 640->493us.  R5: bf16 aggr + wide gather. ->442us.
// R6: fixed-width slot table, one prep kernel. ->419us.
// R7 FAILED (419->510): per-layer gather+conv fusion; reverted.
// R8: 4-byte packed slots. ->415us.
// R9: LDS-bucketed prep, 2B slots, exact f32 he. ->391us.
// R10 NULL (->387.6): 2x gather MLP + speculative loads.
// R11 FAILED (->1241): cooperative all-layer fusion; grid.sync() flushes
//     per-XCD L2 -> 391MB refetch/launch. Reverted.
// R12: fused final gather+conv; conv64 16B loads. ->383.
// R13: lane-serial gather (4 nodes x 16 lanes, zero-row padding). ->372.
// R14: MFMA conv (mfma_f32_16x16x32_bf16, Wb frags in prep, he/bias in
//     acc init, LDS-tiled epilogue). ->293.5.
// R15 FAILED (->318.8): src-range two-pass gather (L2 cache blocking).
//     Halving the per-pass read set to 3.2MB (L2-fitting) did NOT speed
//     the reads -> gather was never L2-capacity-bound; the split only
//     added 6 dispatches + aggr partial round-trip + doubled per-node
//     fixed cost (~+4us/layer). Third independent falsification of a
//     gather theory (R10 issue-bound: null; R15 L2-capacity: regression)
//     => gather is at the memory system's random-access floor
//     (~3.6 TB/s effective for 800k random 128B rows). REVERTED to R14.
// R16: pure revert to the R14 source (no bundled experiments).
// ---------------------------------------------------------------------------

typedef __hip_bfloat16 bf16;

#define SLOTW 64   // max degree supported; Poisson(16) max over 50k ~45
#define EPB   4096 // edges per phase-1 tile block
#define NPB   256  // nodes per bucket (dst>>8)
#define CAP   5120 // per-bucket edge capacity (mean 4096, sigma ~64)
#define WBB   24   // W-fragment build blocks: 6*4*4*64 threads / 256

typedef __attribute__((ext_vector_type(8))) short short8v;
typedef __attribute__((ext_vector_type(4))) float f32x4;

__device__ inline float b2f(unsigned u) {
    return __uint_as_float(u << 16);
}
__device__ inline unsigned short f2b(float f) {
    union { float f; unsigned u; } v;
    v.f = f;
    unsigned r = v.u + 0x7FFF + ((v.u >> 16) & 1);  // RNE
    return (unsigned short)(r >> 16);
}

// ---------------- phase 1: edge bucketing (+W frags, nf->bf16) ------------
__global__ __launch_bounds__(256) void bucket_kernel(
    const int* __restrict__ src, const int* __restrict__ dst,
    const float* __restrict__ ef, uint2* __restrict__ barr,
    int* __restrict__ bfill, int n_edges, int n_tiles, int n_buckets,
    const float* __restrict__ W1, const float* __restrict__ Wmid,
    bf16* __restrict__ Wb, const float* __restrict__ node_feat,
    bf16* __restrict__ nfb, int n_quads) {
    __shared__ int cnt[256];
    __shared__ int pfx[256];   // inclusive scan of cnt
    __shared__ int gbase[256];
    __shared__ uint2 stage[EPB];
    __shared__ int didx[EPB];

    if (blockIdx.x >= n_tiles) {
        int bx = blockIdx.x - n_tiles;
        if (bx < WBB) {
            // MFMA B-fragment build: Wb[l][kt][nt][lane][j] = W_l[n][k],
            // n = nt*16 + (lane&15), k = kt*32 + (lane>>4)*8 + j.
            int fidx = bx * 256 + threadIdx.x;  // < 6144
            int lane = fidx & 63;
            int nt = (fidx >> 6) & 3;
            int kt = (fidx >> 8) & 3;
            int l = fidx >> 10;
            if (l < 6) {
                int n = nt * 16 + (lane & 15);
                int k0 = kt * 32 + (lane >> 4) * 8;
                const float* Wsrc =
                    (l == 0) ? W1 : Wmid + (size_t)(l - 1) * 64 * 129;
                const float* wp = Wsrc + n * 129 + k0;
                unsigned short us[8];
#pragma unroll
                for (int j = 0; j < 8; ++j) us[j] = f2b(wp[j]);
                uint4 pk;
                pk.x = (unsigned)us[0] | ((unsigned)us[1] << 16);
                pk.y = (unsigned)us[2] | ((unsigned)us[3] << 16);
                pk.z = (unsigned)us[4] | ((unsigned)us[5] << 16);
                pk.w = (unsigned)us[6] | ((unsigned)us[7] << 16);
                ((uint4*)Wb)[fidx] = pk;
            }
        } else {
            int q = (bx - WBB) * 256 + threadIdx.x;
            if (q >= n_quads) return;
            float4 v = ((const float4*)node_feat)[q];
            ushort4 u;
            u.x = f2b(v.x); u.y = f2b(v.y); u.z = f2b(v.z); u.w = f2b(v.w);
            ((ushort4*)nfb)[q] = u;
        }
        return;
    }

    const int t = threadIdx.x;
    cnt[t] = 0;
    __syncthreads();

    const int e0 = blockIdx.x * EPB;
    int b[16];
    int r[16];
    uint2 d[16];
#pragma unroll
    for (int i = 0; i < 16; ++i) {
        int e = e0 + i * 256 + t;
        if (e < n_edges) {
            int dv = dst[e];
            int bb = dv >> 8;
            b[i] = bb;
            uint2 rec;
            rec.x = (unsigned)(src[e] & 0xffff) | ((unsigned)(dv & (NPB - 1)) << 16);
            rec.y = __float_as_uint(ef[e]);
            d[i] = rec;
            r[i] = atomicAdd(&cnt[bb], 1);
        } else {
            b[i] = -1;
        }
    }
    __syncthreads();

    // inclusive Hillis-Steele scan of cnt -> pfx
    pfx[t] = cnt[t];
    __syncthreads();
    for (int off = 1; off < 256; off <<= 1) {
        int add = (t >= off) ? pfx[t - off] : 0;
        __syncthreads();
        pfx[t] += add;
        __syncthreads();
    }

    if (t < n_buckets && cnt[t] > 0) gbase[t] = atomicAdd(&bfill[t], cnt[t]);
    __syncthreads();

    // scatter into LDS stage (dense positions), record global dest index
#pragma unroll
    for (int i = 0; i < 16; ++i) {
        if (b[i] >= 0) {
            int bb = b[i];
            int pos = pfx[bb] - cnt[bb] + r[i];
            stage[pos] = d[i];
            int gi = gbase[bb] + r[i];
            didx[pos] = (gi < CAP) ? bb * CAP + gi : -1;
        }
    }
    __syncthreads();

    // coalesced flush: consecutive positions -> consecutive global addrs
    const int total = pfx[255];
    for (int k = t; k < total; k += 256) {
        int di = didx[k];
        if (di >= 0) barr[di] = stage[k];
    }
}

// ---------------- phase 2: build slot rows + deg + he in LDS --------------
// One block per bucket. Slot padding = index n_nodes (the all-zero row).
// Block 0 also zeroes row N of nfb/hA/hB (workspace is re-poisoned between
// calls, so this must happen every launch).
__global__ __launch_bounds__(512) void build_kernel(
    const uint2* __restrict__ barr, const int* __restrict__ bfill,
    unsigned short* __restrict__ slots, int* __restrict__ deg,
    float* __restrict__ he, bf16* __restrict__ nfb, bf16* __restrict__ hA,
    bf16* __restrict__ hB, int n_nodes) {
    __shared__ unsigned short rows[NPB * SLOTW];  // 32KB
    __shared__ int ldeg[NPB];
    __shared__ float lhe[NPB];
    const int bkt = blockIdx.x;
    const int t = threadIdx.x;
    for (int i = t; i < NPB; i += 512) {
        ldeg[i] = 0;
        lhe[i] = 0.f;
    }
    const unsigned padv = (unsigned)n_nodes & 0xffff;
    const unsigned pat = padv | (padv << 16);
    uint4* rz = (uint4*)rows;
    for (int i = t; i < NPB * SLOTW / 8; i += 512)
        rz[i] = make_uint4(pat, pat, pat, pat);
    if (bkt == 0 && t < 24) {
        int which = t >> 3, q = t & 7;
        unsigned short* base = which == 0 ? (unsigned short*)nfb
                             : which == 1 ? (unsigned short*)hA
                                          : (unsigned short*)hB;
        ((uint4*)(base + (size_t)n_nodes * 64))[q] = make_uint4(0, 0, 0, 0);
    }
    __syncthreads();
    int cnt = bfill[bkt];
    if (cnt > CAP) cnt = CAP;
    const uint2* eb = barr + (size_t)bkt * CAP;
    for (int k = t; k < cnt; k += 512) {
        uint2 rec = eb[k];
        int local = (rec.x >> 16) & (NPB - 1);
        atomicAdd(&lhe[local], __uint_as_float(rec.y));
        int p = atomicAdd(&ldeg[local], 1);
        if (p < SLOTW) rows[local * SLOTW + p] = (unsigned short)(rec.x & 0xffff);
    }
    __syncthreads();
    const int n0 = bkt * NPB;
    int nn = n_nodes - n0;
    if (nn > NPB) nn = NPB;
    if (nn <= 0) return;
    for (int i = t; i < nn; i += 512) {
        deg[n0 + i] = ldeg[i];
        he[n0 + i] = lhe[i];
    }
    const uint4* rsrc = (const uint4*)rows;
    uint4* rdst = (uint4*)(slots + (size_t)n0 * SLOTW);
    for (int i = t; i < nn * 8; i += 512) rdst[i] = rsrc[i];
}

// ---------------- per-layer kernels ---------------------------------------

// R13 gather: wave = 4 nodes x 16 feature-lanes; lane serially accumulates
// 4 features, 4 edges/iter (broadcast uint2 slot read + 4 independent 8B
// row loads). Padding hits the all-zero row at index N -> no predication.
__global__ __launch_bounds__(256) void gather_aggr_kernel(
    const bf16* __restrict__ h, const int* __restrict__ deg,
    const unsigned short* __restrict__ slots, bf16* __restrict__ aggr,
    int n_nodes) {
    const int lane = threadIdx.x & 63;
    const int wave = threadIdx.x >> 6;
    int node = blockIdx.x * 16 + wave * 4 + (lane >> 4);
    const int nc = node < n_nodes ? node : n_nodes - 1;
    const int fo = (lane & 15) * 4;  // 4 bf16 = 8B per lane

    int e = deg[nc];
    e = e < SLOTW ? e : SLOTW;
    int it = (e + 3) >> 2;
    {
        int o = __shfl_xor(it, 16, 64);
        it = it > o ? it : o;
        o = __shfl_xor(it, 32, 64);
        it = it > o ? it : o;
    }
    if (it < 1) it = 1;

    const uint2* srow = (const uint2*)(slots + (size_t)nc * SLOTW);
    const unsigned short* hs = (const unsigned short*)h;

    float a0 = 0.f, a1 = 0.f, a2 = 0.f, a3 = 0.f;
    int t = 0;
    do {
        uint2 s = srow[t];  // broadcast across the 16-lane group
        unsigned p0 = s.x & 0xffff, p1 = s.x >> 16;
        unsigned p2 = s.y & 0xffff, p3 = s.y >> 16;
        uint2 u0 = *(const uint2*)(hs + (size_t)p0 * 64 + fo);
        uint2 u1 = *(const uint2*)(hs + (size_t)p1 * 64 + fo);
        uint2 u2 = *(const uint2*)(hs + (size_t)p2 * 64 + fo);
        uint2 u3 = *(const uint2*)(hs + (size_t)p3 * 64 + fo);
        a0 += (b2f(u0.x & 0xffff) + b2f(u1.x & 0xffff)) +
              (b2f(u2.x & 0xffff) + b2f(u3.x & 0xffff));
        a1 += (b2f(u0.x >> 16) + b2f(u1.x >> 16)) +
              (b2f(u2.x >> 16) + b2f(u3.x >> 16));
        a2 += (b2f(u0.y & 0xffff) + b2f(u1.y & 0xffff)) +
              (b2f(u2.y & 0xffff) + b2f(u3.y & 0xffff));
        a3 += (b2f(u0.y >> 16) + b2f(u1.y >> 16)) +
              (b2f(u2.y >> 16) + b2f(u3.y >> 16));
    } while (++t < it);

    if (node < n_nodes) {
        uint2 pk;
        pk.x = (unsigned)f2b(a0) | ((unsigned)f2b(a1) << 16);
        pk.y = (unsigned)f2b(a2) | ((unsigned)f2b(a3) << 16);
        *(uint2*)((unsigned short*)aggr + (size_t)node * 64 + fo) = pk;
    }
}

// R14 MFMA conv: block = 64 nodes, 4 waves; wave computes 16-row stripe of
// C = [h|aggr][64x128] @ W[128x64] via 4kt x 4nt mfma_f32_16x16x32_bf16.
// A-frag: lane row = l&15, k-chunk = l>>4 (16B uint4 from h/aggr row).
// B-frag: precomputed Wb (lane n = l&15, k-chunk = l>>4).
// C/D: col n = nt*16 + (l&15), row m = (l>>4)*4 + reg.
// acc init folds bias + he*W[:,128]. Epilogue: act -> bf16 -> LDS tile
// (stride 72 ushort = 144B) -> coalesced uint4 stores.
__global__ __launch_bounds__(256) void conv_mfma_kernel(
    const bf16* __restrict__ h, const bf16* __restrict__ aggr,
    const float* __restrict__ he, const bf16* __restrict__ Wb,
    const float* __restrict__ Wraw, const float* __restrict__ b,
    bf16* __restrict__ out, int n_nodes, int act) {
    __shared__ __align__(16) unsigned short tile[4][16][72];
    const int lane = threadIdx.x & 63;
    const int w = threadIdx.x >> 6;
    const int nblk = blockIdx.x * 64 + w * 16;  // stripe base node

    int arow_n = nblk + (lane & 15);
    int arn = arow_n < n_nodes ? arow_n : n_nodes - 1;
    const int chunk = lane >> 4;
    const uint4* hrow = (const uint4*)(h + (size_t)arn * 64);
    const uint4* grow = (const uint4*)(aggr + (size_t)arn * 64);

    union AU { uint4 u; short8v s; };
    AU a[4];
    a[0].u = hrow[chunk];
    a[1].u = hrow[4 + chunk];
    a[2].u = grow[chunk];
    a[3].u = grow[4 + chunk];

    f32x4 acc[4];
    float hev[4];
    const int mb = nblk + (lane >> 4) * 4;
#pragma unroll
    for (int i = 0; i < 4; ++i) {
        int rr = mb + i;
        hev[i] = he[rr < n_nodes ? rr : n_nodes - 1];
    }
#pragma unroll
    for (int nt = 0; nt < 4; ++nt) {
        int n = nt * 16 + (lane & 15);
        float bb = b[n];
        float wh = Wraw[n * 129 + 128];
#pragma unroll
        for (int i = 0; i < 4; ++i) acc[nt][i] = bb + hev[i] * wh;
    }

    const uint4* wb4 = (const uint4*)Wb;
#pragma unroll
    for (int kt = 0; kt < 4; ++kt) {
#pragma unroll
        for (int nt = 0; nt < 4; ++nt) {
            AU bf;
            bf.u = wb4[(kt * 4 + nt) * 64 + lane];
            acc[nt] = __builtin_amdgcn_mfma_f32_16x16x32_bf16(
                a[kt].s, bf.s, acc[nt], 0, 0, 0);
        }
    }

#pragma unroll
    for (int nt = 0; nt < 4; ++nt) {
#pragma unroll
        for (int i = 0; i < 4; ++i) {
            float v = acc[nt][i];
            v = (act == 1) ? fmaxf(v, 0.f) : 1.f / (1.f + expf(-v));
            tile[w][(lane >> 4) * 4 + i][nt * 16 + (lane & 15)] = f2b(v);
        }
    }
    __syncthreads();
    const int rr = lane >> 2, cc = lane & 3;
    int nodeo = nblk + rr;
    if (nodeo < n_nodes) {
        uint4* orow = (uint4*)((unsigned short*)out + (size_t)nodeo * 64);
        orow[cc] = *(const uint4*)&tile[w][rr][cc * 8];
        orow[cc + 4] = *(const uint4*)&tile[w][rr][(cc + 4) * 8];
    }
}

// R13 fused final layer: gather (aggr in f32 regs) + per-lane 4-feature dot
// + 16-lane shuffle reduce.
__global__ __launch_bounds__(256) void final_fused_kernel(
    const bf16* __restrict__ h, const int* __restrict__ deg,
    const unsigned short* __restrict__ slots, const float* __restrict__ he,
    const float* __restrict__ W2, const float* __restrict__ b2,
    float* __restrict__ out, int n_nodes) {
    const int lane = threadIdx.x & 63;
    const int wave = threadIdx.x >> 6;
    int node = blockIdx.x * 16 + wave * 4 + (lane >> 4);
    const int nc = node < n_nodes ? node : n_nodes - 1;
    const int fl = lane & 15;
    const int fo = fl * 4;

    int e = deg[nc];
    e = e < SLOTW ? e : SLOTW;
    int it = (e + 3) >> 2;
    {
        int o = __shfl_xor(it, 16, 64);
        it = it > o ? it : o;
        o = __shfl_xor(it, 32, 64);
        it = it > o ? it : o;
    }
    if (it < 1) it = 1;

    const uint2* srow = (const uint2*)(slots + (size_t)nc * SLOTW);
    const unsigned short* hs = (const unsigned short*)h;

    float a0 = 0.f, a1 = 0.f, a2 = 0.f, a3 = 0.f;
    int t = 0;
    do {
        uint2 s = srow[t];
        unsigned p0 = s.x & 0xffff, p1 = s.x >> 16;
        unsigned p2 = s.y & 0xffff, p3 = s.y >> 16;
        uint2 u0 = *(const uint2*)(hs + (size_t)p0 * 64 + fo);
        uint2 u1 = *(const uint2*)(hs + (size_t)p1 * 64 + fo);
        uint2 u2 = *(const uint2*)(hs + (size_t)p2 * 64 + fo);
        uint2 u3 = *(const uint2*)(hs + (size_t)p3 * 64 + fo);
        a0 += (b2f(u0.x & 0xffff) + b2f(u1.x & 0xffff)) +
              (b2f(u2.x & 0xffff) + b2f(u3.x & 0xffff));
        a1 += (b2f(u0.x >> 16) + b2f(u1.x >> 16)) +
              (b2f(u2.x >> 16) + b2f(u3.x >> 16));
        a2 += (b2f(u0.y & 0xffff) + b2f(u1.y & 0xffff)) +
              (b2f(u2.y & 0xffff) + b2f(u3.y & 0xffff));
        a3 += (b2f(u0.y >> 16) + b2f(u1.y >> 16)) +
              (b2f(u2.y >> 16) + b2f(u3.y >> 16));
    } while (++t < it);

    uint2 hu = *(const uint2*)(hs + (size_t)nc * 64 + fo);
    float h0 = b2f(hu.x & 0xffff), h1 = b2f(hu.x >> 16);
    float h2 = b2f(hu.y & 0xffff), h3 = b2f(hu.y >> 16);
    const int f = fo;
    float s0 = W2[f] * h0 + W2[f + 1] * h1 + W2[f + 2] * h2 + W2[f + 3] * h3 +
               W2[64 + f] * a0 + W2[65 + f] * a1 + W2[66 + f] * a2 +
               W2[67 + f] * a3;
    float s1 = W2[129 + f] * h0 + W2[130 + f] * h1 + W2[131 + f] * h2 +
               W2[132 + f] * h3 + W2[193 + f] * a0 + W2[194 + f] * a1 +
               W2[195 + f] * a2 + W2[196 + f] * a3;
#pragma unroll
    for (int off = 1; off < 16; off <<= 1) {
        s0 += __shfl_xor(s0, off, 64);
        s1 += __shfl_xor(s1, off, 64);
    }
    if (fl == 0 && node < n_nodes) {
        float hev = he[node];
        out[(size_t)node * 2] = s0 + W2[128] * hev + b2[0];
        out[(size_t)node * 2 + 1] = s1 + W2[257] * hev + b2[1];
    }
}

extern "C" void kernel_launch(void* const* d_in, const int* in_sizes, int n_in,
                              void* d_out, int out_size, void* d_ws,
                              size_t ws_size, hipStream_t stream) {
    const float* node_feat = (const float*)d_in[0];
    const float* edge_feat = (const float*)d_in[1];
    const int* src = (const int*)d_in[2];
    const int* dst = (const int*)d_in[3];
    const float* W1 = (const float*)d_in[4];
    const float* b1 = (const float*)d_in[5];
    const float* Wmid = (const float*)d_in[6];
    const float* bmid = (const float*)d_in[7];
    const float* W2 = (const float*)d_in[8];
    const float* b2 = (const float*)d_in[9];
    float* out = (float*)d_out;

    const int N = in_sizes[0] / 64;  // 50000
    const int E = in_sizes[1];       // 800000
    const int NBKT = (N + NPB - 1) / NPB;  // 196
    const size_t R = (size_t)(N + 1) * 64;  // rows incl. zero row

    // workspace layout (sections 16B-aligned)
    float* he = (float*)d_ws;                              // N f32
    bf16* Wb = (bf16*)(he + N);                            // 6*8192 bf16
    bf16* aggr = Wb + 6 * 8192;                            // N*64 bf16
    bf16* hA = aggr + (size_t)N * 64;                      // (N+1)*64 bf16
    bf16* hB = hA + R;                                     // (N+1)*64 bf16
    bf16* nfb = hB + R;                                    // (N+1)*64 bf16
    unsigned short* slots = (unsigned short*)(nfb + R);    // N*SLOTW
    int* deg = (int*)(slots + (size_t)N * SLOTW);          // N
    int* bfill = deg + N;                                  // NBKT
    uint2* barr = (uint2*)(((uintptr_t)(bfill + NBKT) + 15) & ~(uintptr_t)15);
    // barr: NBKT*CAP uint2 = ~8 MB; total ~41 MB

    // --- prep ---
    hipMemsetAsync(bfill, 0, (size_t)NBKT * sizeof(int), stream);
    const int n_tiles = (E + EPB - 1) / EPB;
    const int n_quads = N * 16;
    const int CB = (n_quads + 255) / 256;
    bucket_kernel<<<n_tiles + WBB + CB, 256, 0, stream>>>(
        src, dst, edge_feat, barr, bfill, E, n_tiles, NBKT, W1, Wmid, Wb,
        node_feat, nfb, n_quads);
    build_kernel<<<NBKT, 512, 0, stream>>>(barr, bfill, slots, deg, he, nfb,
                                           hA, hB, N);

    // --- 7 layers ---
    const int conv_blocks = (N + 63) / 64;
    const int gather_blocks = (N + 15) / 16;

    // layer 0 (bf16 node features)
    gather_aggr_kernel<<<gather_blocks, 256, 0, stream>>>(nfb, deg, slots,
                                                          aggr, N);
    conv_mfma_kernel<<<conv_blocks, 256, 0, stream>>>(nfb, aggr, he, Wb, W1,
                                                      b1, hA, N, 1);

    // layers 1..5
    bf16* bufs[2] = {hA, hB};
    const bf16* hin = hA;
    for (int l = 1; l < 6; ++l) {
        gather_aggr_kernel<<<gather_blocks, 256, 0, stream>>>(hin, deg, slots,
                                                              aggr, N);
        int act = (l - 1) < 4 ? 1 : 2;  // mid layers 0..3 relu, 4 sigmoid
        bf16* hout = bufs[l & 1];
        conv_mfma_kernel<<<conv_blocks, 256, 0, stream>>>(
            hin, aggr, he, Wb + (size_t)l * 8192,
            Wmid + (size_t)(l - 1) * 64 * 129, bmid + (size_t)(l - 1) * 64,
            hout, N, act);
        hin = hout;
    }

    // final layer: fused gather + 2-output conv
    final_fused_kernel<<<gather_blocks, 256, 0, stream>>>(hin, deg, slots, he,
                                                          W2, b2, out, N);
}